// Round 17
// baseline (1727.967 us; speedup 1.0000x reference)
//
#include <hip/hip_runtime.h>
#include <math.h>

#define HDIM 256
#define NLAYERS 6

typedef __attribute__((ext_vector_type(8))) short short8v;
typedef __attribute__((ext_vector_type(16))) float f32x16;

__device__ __forceinline__ float silu_(float x){ return x * (1.f/(1.f+__expf(-x))); }

__device__ __forceinline__ unsigned short f2bf(float f){
  unsigned u = __float_as_uint(f);
  u += 0x7FFF + ((u>>16)&1);
  return (unsigned short)(u>>16);
}
__device__ __forceinline__ float bf2f(unsigned short b){ return __uint_as_float(((unsigned)b)<<16); }

__device__ __forceinline__ void gload_lds16(const void* g, void* l){
  __builtin_amdgcn_global_load_lds((const __attribute__((address_space(1))) void*)g,
                                   (__attribute__((address_space(3))) void*)l, 16, 0, 0);
}

// ---------------- degree counting ----------------
__global__ void k_count(const int* __restrict__ src, const int* __restrict__ dst, int E,
                        int* __restrict__ cnt_out, int* __restrict__ cnt_in){
  int e = blockIdx.x*256 + threadIdx.x;
  if(e < E){
    atomicAdd(&cnt_out[src[e]], 1);
    atomicAdd(&cnt_in[dst[e]], 1);
  }
}

// ---------------- multi-block exclusive scan of cnt_in -> csr_off ----------------
__global__ __launch_bounds__(256) void k_scan1(const int* __restrict__ cnt_in,
                                               int* __restrict__ partial, int N){
  __shared__ int s[256];
  int b = blockIdx.x, tid = threadIdx.x;
  int i0 = b*1024 + tid*4;
  int sum = 0;
  #pragma unroll
  for(int j=0;j<4;j++){ int i=i0+j; if(i<N) sum += cnt_in[i]; }
  s[tid] = sum; __syncthreads();
  for(int off=128; off; off>>=1){ if(tid<off) s[tid]+=s[tid+off]; __syncthreads(); }
  if(tid==0) partial[b] = s[0];
}
__global__ __launch_bounds__(256) void k_scan2(int* __restrict__ partial,
                                               int* __restrict__ csr_off, int nb, int N){
  __shared__ int s[256];
  int tid = threadIdx.x;
  int v = (tid<nb) ? partial[tid] : 0;
  s[tid] = v; __syncthreads();
  for(int off=1; off<256; off<<=1){
    int t = (tid>=off) ? s[tid-off] : 0;
    __syncthreads(); s[tid] += t; __syncthreads();
  }
  if(tid<nb) partial[tid] = s[tid] - v;
  if(tid==255) csr_off[N] = s[255];
}
__global__ __launch_bounds__(256) void k_scan3(const int* __restrict__ cnt_in,
                                               const int* __restrict__ partial,
                                               int* __restrict__ csr_off, int N){
  __shared__ int s[256];
  int b = blockIdx.x, tid = threadIdx.x;
  int i0 = b*1024 + tid*4;
  int c[4];
  #pragma unroll
  for(int j=0;j<4;j++){ int i=i0+j; c[j] = (i<N) ? cnt_in[i] : 0; }
  int tot = c[0]+c[1]+c[2]+c[3];
  s[tid] = tot; __syncthreads();
  for(int off=1; off<256; off<<=1){
    int t = (tid>=off) ? s[tid-off] : 0;
    __syncthreads(); s[tid] += t; __syncthreads();
  }
  int run = s[tid] - tot + partial[b];
  #pragma unroll
  for(int j=0;j<4;j++){
    int i = i0+j;
    if(i<N) csr_off[i] = run;
    run += c[j];
  }
}

// ---------------- norms + csr fill pointer + per-graph node count ----------------
__global__ void k_prep(const int* __restrict__ cnt_out, const int* __restrict__ cnt_in,
                       const int* __restrict__ csr_off, const int* __restrict__ n_index,
                       float* __restrict__ no, float* __restrict__ ni,
                       int* __restrict__ csr_pos, int* __restrict__ gcnt, int N){
  int v = blockIdx.x*256 + threadIdx.x;
  if(v < N){
    no[v] = rsqrtf((float)max(cnt_out[v],1));
    ni[v] = rsqrtf((float)max(cnt_in[v],1));
    csr_pos[v] = csr_off[v];
    atomicAdd(&gcnt[n_index[v]], 1);
  }
}

__global__ void k_fill(const int* __restrict__ src, const int* __restrict__ dst, int E,
                       int* __restrict__ csr_pos, int* __restrict__ csr_src,
                       int* __restrict__ csr_eid){
  int e = blockIdx.x*256 + threadIdx.x;
  if(e < E){
    int p = atomicAdd(&csr_pos[dst[e]], 1);
    csr_src[p] = src[e];
    csr_eid[p] = e;
  }
}

// ---------------- time embedding + MLP -> cond ----------------
__global__ __launch_bounds__(256) void k_cond(const float* __restrict__ t,
        const float* __restrict__ w1, const float* __restrict__ b1,
        const float* __restrict__ w2, const float* __restrict__ b2,
        float* __restrict__ cond){
  __shared__ float emb[128];
  __shared__ float hid[256];
  int b = blockIdx.x, tid = threadIdx.x;
  float tv = t[b] * 1000.f;
  if(tid < 128){
    int k = tid & 63;
    float fr = expf(-logf(1000.f) * (float)k * (1.f/64.f));
    float a = tv * fr;
    emb[tid] = (tid < 64) ? sinf(a) : cosf(a);
  }
  __syncthreads();
  {
    float s = b1[tid];
    for(int k=0;k<128;k++) s += emb[k] * w1[k*HDIM + tid];
    hid[tid] = silu_(s);
  }
  __syncthreads();
  {
    float s = b2[tid];
    for(int k=0;k<256;k++) s += hid[k] * w2[k*HDIM + tid];
    cond[(size_t)b*HDIM + tid] = s;
  }
}

// ---------------- generic f32 tiled GEMM: 64 rows x 256 cols per block ----------------
template<int K>
__global__ __launch_bounds__(256) void k_gemm_f32(
    const float* __restrict__ A, int lda,
    const float* __restrict__ W, int ldw,
    const float* __restrict__ bias,
    float* __restrict__ out, int ldo, int M, int mode,
    unsigned short* __restrict__ out_bf){
  if(mode == 1){
    int c = blockIdx.y;
    W    += (size_t)(c>>1)*131072 + (size_t)(c&1)*256;
    bias += (size_t)(c>>1)*512 + (size_t)(c&1)*256;
    out  += (size_t)c*1024*256;
  }
  __shared__ float As[64][36];
  __shared__ float Ws[32][256];
  const int tid = threadIdx.x;
  const int rg = tid >> 4;
  const int cg = tid & 15;
  const int row0 = blockIdx.x * 64;

  float4 acc[4][4];
  #pragma unroll
  for(int i=0;i<4;i++)
    #pragma unroll
    for(int m=0;m<4;m++) acc[i][m] = make_float4(0.f,0.f,0.f,0.f);

  const int ar = tid >> 2;
  const int ac = (tid & 3) * 8;
  const int wr = tid >> 3;
  const int wc = (tid & 7) * 32;

  for(int kk=0; kk<K; kk+=32){
    {
      int gr = row0 + ar;
      float4 v0 = make_float4(0.f,0.f,0.f,0.f), v1 = v0;
      if(gr < M){
        v0 = *(const float4*)&A[(size_t)gr*lda + kk + ac];
        v1 = *(const float4*)&A[(size_t)gr*lda + kk + ac + 4];
      }
      *(float4*)&As[ar][ac]   = v0;
      *(float4*)&As[ar][ac+4] = v1;
    }
    #pragma unroll
    for(int u=0;u<8;u++)
      *(float4*)&Ws[wr][wc + u*4] = *(const float4*)&W[(size_t)(kk+wr)*ldw + wc + u*4];
    __syncthreads();
    #pragma unroll 8
    for(int k=0;k<32;k++){
      float a0 = As[rg*4+0][k];
      float a1 = As[rg*4+1][k];
      float a2 = As[rg*4+2][k];
      float a3 = As[rg*4+3][k];
      #pragma unroll
      for(int m=0;m<4;m++){
        float4 w = *(const float4*)&Ws[k][cg*4 + m*64];
        acc[0][m].x += a0*w.x; acc[0][m].y += a0*w.y; acc[0][m].z += a0*w.z; acc[0][m].w += a0*w.w;
        acc[1][m].x += a1*w.x; acc[1][m].y += a1*w.y; acc[1][m].z += a1*w.z; acc[1][m].w += a1*w.w;
        acc[2][m].x += a2*w.x; acc[2][m].y += a2*w.y; acc[2][m].z += a2*w.z; acc[2][m].w += a2*w.w;
        acc[3][m].x += a3*w.x; acc[3][m].y += a3*w.y; acc[3][m].z += a3*w.z; acc[3][m].w += a3*w.w;
      }
    }
    __syncthreads();
  }

  const int c0 = cg * 4;
  #pragma unroll
  for(int i=0;i<4;i++){
    const int gr = row0 + rg*4 + i;
    if(gr >= M) continue;
    #pragma unroll
    for(int m=0;m<4;m++){
      const int c = c0 + m*64;
      float4 b4 = *(const float4*)&bias[c];
      float4 o = make_float4(acc[i][m].x+b4.x, acc[i][m].y+b4.y,
                             acc[i][m].z+b4.z, acc[i][m].w+b4.w);
      if(out) *(float4*)&out[(size_t)gr*ldo + c] = o;
      if(out_bf)
        *(ushort4*)&out_bf[(size_t)gr*ldo + c] =
            make_ushort4(f2bf(o.x), f2bf(o.y), f2bf(o.z), f2bf(o.w));
    }
  }
}

// ---------------- build stacked init weight [64][256] ----------------
__global__ void k_wcat(const float* __restrict__ in_w, const float* __restrict__ ew,
                       const float* __restrict__ eb, float* __restrict__ wcat){
  int idx = blockIdx.x*256 + threadIdx.x;
  int r = idx>>8, c = idx&255;
  float v = 0.f;
  if(r < 32) v = in_w[r*HDIM + c];
  else if(r < 48) v = ew[(r-32)*HDIM + c];
  else if(r == 48) v = eb[c];
  wcat[idx] = v;
}

// ---------------- prepack conv2_w: transpose + bf16 hi/lo split ----------------
__global__ void k_w2b(const float* __restrict__ W, unsigned short* __restrict__ hi_,
                      unsigned short* __restrict__ lo_){
  int idx = blockIdx.x*256 + threadIdx.x;   // 6*65536
  int i = idx >> 16, r = idx & 65535;
  int n = r >> 8, k = r & 255;
  float v = W[((size_t)i*256 + k)*256 + n];
  unsigned short h = f2bf(v);
  float lo = v - bf2f(h);
  hi_[((size_t)i*256 + n)*256 + k] = h;
  lo_[((size_t)i*256 + n)*256 + k] = f2bf(lo);
}

// ---------------- init aggregation ----------------
__global__ __launch_bounds__(256) void k_init_agg(const float* __restrict__ node_x,
    const float* __restrict__ edge_e,
    const int* __restrict__ csr_off, const int* __restrict__ csr_src, const int* __restrict__ csr_eid,
    const float* __restrict__ no, const float* __restrict__ ni, const int* __restrict__ cnt_in,
    float* __restrict__ A48, int N){
  int v = blockIdx.x*4 + (threadIdx.x>>6);
  if(v >= N) return;
  int lane = threadIdx.x & 63;
  int beg = csr_off[v], end = csr_off[v+1];
  float acc = 0.f;
  for(int p=beg; p<end; p++){
    int s = csr_src[p]; int e = csr_eid[p];
    if(lane < 32)      acc += node_x[(size_t)s*32 + lane] * no[s];
    else if(lane < 48) acc += edge_e[(size_t)e*16 + (lane-32)];
  }
  int ci = cnt_in[v];
  float out;
  if(lane < 32)      out = acc * ni[v];
  else if(lane < 48) out = acc * (1.f/(float)max(ci,1));
  else if(lane == 48) out = (ci>0) ? 1.f : 0.f;
  else out = 0.f;
  A48[(size_t)v*64 + lane] = out;
}

// ---------------- per-layer gather: 1 row per wave, bf16 h -> bf16 agg ----------------
__global__ __launch_bounds__(256) void k_gather_bf(const unsigned short* __restrict__ hbf,
   const int* __restrict__ csr_off, const int* __restrict__ csr_src,
   const float* __restrict__ no, const float* __restrict__ ni,
   unsigned short* __restrict__ ahi, int N, int Npad){
  int v = blockIdx.x*4 + (threadIdx.x>>6);
  if(v >= Npad) return;
  int lane = threadIdx.x & 63;
  float4 acc = make_float4(0.f,0.f,0.f,0.f);
  if(v < N){
    int beg = csr_off[v], end = csr_off[v+1];
    for(int p=beg; p<end; p++){
      int s = csr_src[p];
      float w = no[s];
      ushort4 x = *(const ushort4*)&hbf[(size_t)s*HDIM + lane*4];
      acc.x += bf2f(x.x)*w; acc.y += bf2f(x.y)*w;
      acc.z += bf2f(x.z)*w; acc.w += bf2f(x.w)*w;
    }
    float sc = ni[v];
    acc.x*=sc; acc.y*=sc; acc.z*=sc; acc.w*=sc;
  }
  ushort4 hv = make_ushort4(f2bf(acc.x), f2bf(acc.y), f2bf(acc.z), f2bf(acc.w));
  *(ushort4*)&ahi[(size_t)v*HDIM + lane*4] = hv;
}

// ---------------- layer GEMM: 32-row tiles, 6 blocks/CU (24 waves) for miss concurrency ----------------
// block = 256 thr = 4 waves; tile 32 rows x 256 cols; wave tile 32x64 (1x2 of 32x32)
// LDS 16KB used (A stage aliased by 16-row z-buffer), padded to 24KB -> 6 blocks/CU.
template<bool LAST>
__global__ __launch_bounds__(256, 6) void k_layer_mfma(
    const unsigned short* __restrict__ Ahi,
    const unsigned short* __restrict__ Bhi, const unsigned short* __restrict__ Blo,
    const float* __restrict__ bias, const float* __restrict__ lng, const float* __restrict__ lnb,
    const float* __restrict__ gamL, const float* __restrict__ betL,
    const int* __restrict__ n_index, unsigned short* __restrict__ hbf,
    const float* __restrict__ hw, float* __restrict__ gsum, int N){
  __shared__ __align__(16) char smem[24576];   // 16KB used; padded -> 6 blocks/CU
  float* zbuf = (float*)smem;
  const int tid = threadIdx.x;
  const int w = tid >> 6, l = tid & 63;
  const int half = l >> 5, lcol = l & 31;
  const int row0 = blockIdx.x * 32;
  const int colb = w * 64;
  const size_t bb = (size_t)(colb + lcol)*HDIM + half*8;

  // B prefetch: 2 rotating slots (TLP at 24 waves/CU covers the rest)
  short8v Bh0[2], Bh1[2], Bl0[2], Bl1[2];
  #define LOADB(t, s) { \
    Bh0[s] = *(const short8v*)&Bhi[bb + (t)*16]; \
    Bh1[s] = *(const short8v*)&Bhi[bb + 32*HDIM + (t)*16]; \
    Bl0[s] = *(const short8v*)&Blo[bb + (t)*16]; \
    Bl1[s] = *(const short8v*)&Blo[bb + 32*HDIM + (t)*16]; }
  LOADB(0,0) LOADB(1,1)

  // stage A tile (bf16): 32 rows x 256 k = 16KB; 4 chunks x (256 thr * 16B), swizzled source
  {
    const int m = tid & 31;
    const int rofs = tid >> 5;
    #pragma unroll
    for(int chunk=0; chunk<4; chunk++){
      const int row = chunk*8 + rofs;                       // 0..31
      const int msw = (m & 24) | ((m ^ row) & 7);
      const size_t src = (size_t)(row0 + row)*HDIM + msw*8;
      gload_lds16(&Ahi[src], (char*)smem + chunk*4096 + tid*16);
    }
  }
  __syncthreads();

  f32x16 acc0 = {}, acc1 = {};
  const char* baseH = (const char*)smem;

  #pragma unroll
  for(int t=0; t<16; t++){
    if(t < 15) LOADB(t+1, (t+1)&1)
    const int s = t & 1;
    const int g = t*2 + half;
    const int slot = (g & 24) | ((g ^ lcol) & 7);
    short8v ah0 = *(const short8v*)(baseH + lcol*512 + slot*16);
    acc0 = __builtin_amdgcn_mfma_f32_32x32x16_bf16(ah0, Bh0[s], acc0, 0,0,0);
    acc1 = __builtin_amdgcn_mfma_f32_32x32x16_bf16(ah0, Bh1[s], acc1, 0,0,0);
    acc0 = __builtin_amdgcn_mfma_f32_32x32x16_bf16(ah0, Bl0[s], acc0, 0,0,0);
    acc1 = __builtin_amdgcn_mfma_f32_32x32x16_bf16(ah0, Bl1[s], acc1, 0,0,0);
  }
  #undef LOADB

  // ---- epilogue: 2 passes of 16 rows via aliased 16KB f32 z-buffer ----
  float bias_c[2];
  bias_c[0] = bias[colb + lcol];
  bias_c[1] = bias[colb + 32 + lcol];
  const int qr = l >> 4, lc = l & 15;

  #pragma unroll
  for(int pass=0; pass<2; pass++){
    __syncthreads();   // pass0: A reads done; pass1: previous z reads done
    #pragma unroll
    for(int r=0; r<8; r++){
      const int rr = pass*8 + r;
      const int rl = (rr&3) + 8*((rr>>2)&1) + 4*half;    // local row 0..15
      zbuf[rl*HDIM + colb      + lcol] = acc0[rr] + bias_c[0];
      zbuf[rl*HDIM + colb + 32 + lcol] = acc1[rr] + bias_c[1];
    }
    __syncthreads();
    {
      const int row = w*4 + qr;                          // local row 0..15
      const int grow = row0 + pass*16 + row;
      const bool ok = grow < N;
      const int bidx = ok ? n_index[grow] : 0;
      float4 z[4];
      #pragma unroll
      for(int j=0;j<4;j++) z[j] = *(const float4*)&zbuf[row*HDIM + lc*4 + j*64];
      float s = 0.f, q = 0.f;
      #pragma unroll
      for(int j=0;j<4;j++){
        s += z[j].x + z[j].y + z[j].z + z[j].w;
        q += z[j].x*z[j].x + z[j].y*z[j].y + z[j].z*z[j].z + z[j].w*z[j].w;
      }
      #pragma unroll
      for(int off=1; off<16; off<<=1){ s += __shfl_xor(s, off, 16); q += __shfl_xor(q, off, 16); }
      const float mu = s * (1.f/256.f);
      const float rs = rsqrtf(fmaxf(q*(1.f/256.f) - mu*mu, 0.f) + 1e-5f);
      float rd = 0.f;
      #pragma unroll
      for(int j=0;j<4;j++){
        const int c = lc*4 + j*64;
        const float4 lg = *(const float4*)&lng[c];
        const float4 lb = *(const float4*)&lnb[c];
        const float4 g4 = *(const float4*)&gamL[(size_t)bidx*HDIM + c];
        const float4 b4 = *(const float4*)&betL[(size_t)bidx*HDIM + c];
        float4 o;
        float zn;
        zn = (z[j].x-mu)*rs*lg.x + lb.x; o.x = silu_(zn*(1.f+g4.x)+b4.x);
        zn = (z[j].y-mu)*rs*lg.y + lb.y; o.y = silu_(zn*(1.f+g4.y)+b4.y);
        zn = (z[j].z-mu)*rs*lg.z + lb.z; o.z = silu_(zn*(1.f+g4.z)+b4.z);
        zn = (z[j].w-mu)*rs*lg.w + lb.w; o.w = silu_(zn*(1.f+g4.w)+b4.w);
        if(LAST){
          ushort4 hv = ok ? *(const ushort4*)&hbf[(size_t)grow*HDIM + c]
                          : make_ushort4(0,0,0,0);
          const float4 w4 = *(const float4*)&hw[c];
          rd += (o.x+bf2f(hv.x))*w4.x + (o.y+bf2f(hv.y))*w4.y
              + (o.z+bf2f(hv.z))*w4.z + (o.w+bf2f(hv.w))*w4.w;
        } else {
          if(ok){
            ushort4 hv = *(const ushort4*)&hbf[(size_t)grow*HDIM + c];
            float ox = o.x + bf2f(hv.x), oy = o.y + bf2f(hv.y);
            float oz = o.z + bf2f(hv.z), ow = o.w + bf2f(hv.w);
            *(ushort4*)&hbf[(size_t)grow*HDIM + c] =
                make_ushort4(f2bf(ox), f2bf(oy), f2bf(oz), f2bf(ow));
          }
        }
      }
      if(LAST){
        #pragma unroll
        for(int off=1; off<16; off<<=1) rd += __shfl_xor(rd, off, 16);
        if(lc == 0 && ok) atomicAdd(&gsum[bidx], rd);
      }
    }
  }
}

__global__ void k_final(const float* __restrict__ gsum, const int* __restrict__ gcnt,
                        const float* __restrict__ hb, float* __restrict__ out, int B){
  int b = blockIdx.x*256 + threadIdx.x;
  if(b < B) out[b] = gsum[b] / (float)max(gcnt[b],1) + hb[0];
}

extern "C" void kernel_launch(void* const* d_in, const int* in_sizes, int n_in,
                              void* d_out, int out_size, void* d_ws, size_t ws_size,
                              hipStream_t stream){
  const float* node_x   = (const float*)d_in[0];
  const float* edge_e   = (const float*)d_in[1];
  const float* t        = (const float*)d_in[2];
  const int*   n_index  = (const int*)d_in[3];
  const int*   src      = (const int*)d_in[4];
  const int*   dst      = (const int*)d_in[5];
  const float* in_conv_w= (const float*)d_in[6];
  const float* in_conv_b= (const float*)d_in[7];
  const float* edge_w   = (const float*)d_in[8];
  const float* edge_b   = (const float*)d_in[9];
  const float* t_w1     = (const float*)d_in[10];
  const float* t_b1     = (const float*)d_in[11];
  const float* t_w2     = (const float*)d_in[12];
  const float* t_b2     = (const float*)d_in[13];
  const float* conv2_w  = (const float*)d_in[16];
  const float* conv2_b  = (const float*)d_in[17];
  const float* ln2_g    = (const float*)d_in[20];
  const float* ln2_b    = (const float*)d_in[21];
  const float* film2_w  = (const float*)d_in[24];
  const float* film2_b  = (const float*)d_in[25];
  const float* head_w   = (const float*)d_in[26];
  const float* head_b   = (const float*)d_in[27];

  const int N = in_sizes[3];
  const int E = in_sizes[4];
  const int B = in_sizes[2];
  const int Npad = (N + 63) & ~63;

  char* w = (char*)d_ws;
  auto alloc = [&](size_t bytes)->char*{
    char* p = w; w += (bytes + 255) & ~(size_t)255; return p;
  };
  int*   cnt_out = (int*)  alloc((size_t)N*4);
  int*   cnt_in  = (int*)  alloc((size_t)N*4);
  float* no      = (float*)alloc((size_t)N*4);
  float* ni      = (float*)alloc((size_t)N*4);
  int*   csr_off = (int*)  alloc((size_t)(N+1)*4);
  int*   csr_pos = (int*)  alloc((size_t)N*4);
  int*   csr_src = (int*)  alloc((size_t)E*4);
  int*   csr_eid = (int*)  alloc((size_t)E*4);
  int*   partial = (int*)  alloc((size_t)256*4);
  float* cond    = (float*)alloc((size_t)B*HDIM*4);
  float* gbX     = (float*)alloc((size_t)12*B*HDIM*4);
  float* gsum    = (float*)alloc((size_t)B*4);
  int*   gcnt    = (int*)  alloc((size_t)B*4);
  unsigned short* hbf    = (unsigned short*)alloc((size_t)Npad*HDIM*2);
  unsigned short* agg_hi = (unsigned short*)alloc((size_t)Npad*HDIM*2);
  unsigned short* Wthi   = (unsigned short*)alloc((size_t)NLAYERS*HDIM*HDIM*2);
  unsigned short* Wtlo   = (unsigned short*)alloc((size_t)NLAYERS*HDIM*HDIM*2);
  float* wcat    = (float*)alloc((size_t)64*HDIM*4);
  float* A48     = (float*)alloc((size_t)Npad*64*4);

  hipMemsetAsync(cnt_out, 0, (size_t)N*4, stream);
  hipMemsetAsync(cnt_in,  0, (size_t)N*4, stream);
  hipMemsetAsync(gsum,    0, (size_t)B*4, stream);
  hipMemsetAsync(gcnt,    0, (size_t)B*4, stream);

  int gE = (E+255)/256, gN = (N+255)/256;
  int nb1 = (N+1023)/1024;
  k_count<<<gE,256,0,stream>>>(src, dst, E, cnt_out, cnt_in);
  k_scan1<<<nb1,256,0,stream>>>(cnt_in, partial, N);
  k_scan2<<<1,256,0,stream>>>(partial, csr_off, nb1, N);
  k_scan3<<<nb1,256,0,stream>>>(cnt_in, partial, csr_off, N);
  k_prep<<<gN,256,0,stream>>>(cnt_out, cnt_in, csr_off, n_index, no, ni, csr_pos, gcnt, N);
  k_fill<<<gE,256,0,stream>>>(src, dst, E, csr_pos, csr_src, csr_eid);

  k_cond<<<B,256,0,stream>>>(t, t_w1, t_b1, t_w2, t_b2, cond);
  k_gemm_f32<256><<<dim3(B/64,12),256,0,stream>>>(cond, HDIM, film2_w, 512, film2_b,
                                                  gbX, HDIM, B, 1, nullptr);

  k_w2b<<<NLAYERS*HDIM*HDIM/256,256,0,stream>>>(conv2_w, Wthi, Wtlo);
  k_wcat<<<64,256,0,stream>>>(in_conv_w, edge_w, edge_b, wcat);
  k_init_agg<<<(N+3)/4,256,0,stream>>>(node_x, edge_e, csr_off, csr_src, csr_eid,
                                       no, ni, cnt_in, A48, N);
  k_gemm_f32<64><<<Npad/64,256,0,stream>>>(A48, 64, wcat, HDIM, in_conv_b,
                                           nullptr, HDIM, N, 0, hbf);

  for(int i=0;i<NLAYERS;i++){
    k_gather_bf<<<Npad/4,256,0,stream>>>(hbf, csr_off, csr_src, no, ni, agg_hi, N, Npad);
    if(i < NLAYERS-1)
      k_layer_mfma<false><<<Npad/32,256,0,stream>>>(agg_hi,
          Wthi + (size_t)i*HDIM*HDIM, Wtlo + (size_t)i*HDIM*HDIM,
          conv2_b + (size_t)i*HDIM,
          ln2_g + (size_t)i*HDIM, ln2_b + (size_t)i*HDIM,
          gbX + (size_t)(2*i)*B*HDIM, gbX + (size_t)(2*i+1)*B*HDIM,
          n_index, hbf, head_w, gsum, N);
    else
      k_layer_mfma<true><<<Npad/32,256,0,stream>>>(agg_hi,
          Wthi + (size_t)i*HDIM*HDIM, Wtlo + (size_t)i*HDIM*HDIM,
          conv2_b + (size_t)i*HDIM,
          ln2_g + (size_t)i*HDIM, ln2_b + (size_t)i*HDIM,
          gbX + (size_t)(2*i)*B*HDIM, gbX + (size_t)(2*i+1)*B*HDIM,
          n_index, hbf, head_w, gsum, N);
  }

  k_final<<<(B+255)/256,256,0,stream>>>(gsum, gcnt, head_b, (float*)d_out, B);
}

// Round 18
// 1402.855 us; speedup vs baseline: 1.2318x; 1.2318x over previous
//
#include <hip/hip_runtime.h>
#include <math.h>

#define HDIM 256
#define NLAYERS 6

typedef __attribute__((ext_vector_type(8))) short short8v;
typedef __attribute__((ext_vector_type(16))) float f32x16;

__device__ __forceinline__ float silu_(float x){ return x * (1.f/(1.f+__expf(-x))); }

__device__ __forceinline__ unsigned short f2bf(float f){
  unsigned u = __float_as_uint(f);
  u += 0x7FFF + ((u>>16)&1);
  return (unsigned short)(u>>16);
}
__device__ __forceinline__ float bf2f(unsigned short b){ return __uint_as_float(((unsigned)b)<<16); }

__device__ __forceinline__ void gload_lds16(const void* g, void* l){
  __builtin_amdgcn_global_load_lds((const __attribute__((address_space(1))) void*)g,
                                   (__attribute__((address_space(3))) void*)l, 16, 0, 0);
}

// ---------------- degree counting ----------------
__global__ void k_count(const int* __restrict__ src, const int* __restrict__ dst, int E,
                        int* __restrict__ cnt_out, int* __restrict__ cnt_in){
  int e = blockIdx.x*256 + threadIdx.x;
  if(e < E){
    atomicAdd(&cnt_out[src[e]], 1);
    atomicAdd(&cnt_in[dst[e]], 1);
  }
}

// ---------------- multi-block exclusive scan of cnt_in -> csr_off ----------------
__global__ __launch_bounds__(256) void k_scan1(const int* __restrict__ cnt_in,
                                               int* __restrict__ partial, int N){
  __shared__ int s[256];
  int b = blockIdx.x, tid = threadIdx.x;
  int i0 = b*1024 + tid*4;
  int sum = 0;
  #pragma unroll
  for(int j=0;j<4;j++){ int i=i0+j; if(i<N) sum += cnt_in[i]; }
  s[tid] = sum; __syncthreads();
  for(int off=128; off; off>>=1){ if(tid<off) s[tid]+=s[tid+off]; __syncthreads(); }
  if(tid==0) partial[b] = s[0];
}
__global__ __launch_bounds__(256) void k_scan2(int* __restrict__ partial,
                                               int* __restrict__ csr_off, int nb, int N){
  __shared__ int s[256];
  int tid = threadIdx.x;
  int v = (tid<nb) ? partial[tid] : 0;
  s[tid] = v; __syncthreads();
  for(int off=1; off<256; off<<=1){
    int t = (tid>=off) ? s[tid-off] : 0;
    __syncthreads(); s[tid] += t; __syncthreads();
  }
  if(tid<nb) partial[tid] = s[tid] - v;
  if(tid==255) csr_off[N] = s[255];
}
__global__ __launch_bounds__(256) void k_scan3(const int* __restrict__ cnt_in,
                                               const int* __restrict__ partial,
                                               int* __restrict__ csr_off, int N){
  __shared__ int s[256];
  int b = blockIdx.x, tid = threadIdx.x;
  int i0 = b*1024 + tid*4;
  int c[4];
  #pragma unroll
  for(int j=0;j<4;j++){ int i=i0+j; c[j] = (i<N) ? cnt_in[i] : 0; }
  int tot = c[0]+c[1]+c[2]+c[3];
  s[tid] = tot; __syncthreads();
  for(int off=1; off<256; off<<=1){
    int t = (tid>=off) ? s[tid-off] : 0;
    __syncthreads(); s[tid] += t; __syncthreads();
  }
  int run = s[tid] - tot + partial[b];
  #pragma unroll
  for(int j=0;j<4;j++){
    int i = i0+j;
    if(i<N) csr_off[i] = run;
    run += c[j];
  }
}

// ---------------- norms + csr fill pointer + per-graph node count ----------------
__global__ void k_prep(const int* __restrict__ cnt_out, const int* __restrict__ cnt_in,
                       const int* __restrict__ csr_off, const int* __restrict__ n_index,
                       float* __restrict__ no, float* __restrict__ ni,
                       int* __restrict__ csr_pos, int* __restrict__ gcnt, int N){
  int v = blockIdx.x*256 + threadIdx.x;
  if(v < N){
    no[v] = rsqrtf((float)max(cnt_out[v],1));
    ni[v] = rsqrtf((float)max(cnt_in[v],1));
    csr_pos[v] = csr_off[v];
    atomicAdd(&gcnt[n_index[v]], 1);
  }
}

__global__ void k_fill(const int* __restrict__ src, const int* __restrict__ dst, int E,
                       int* __restrict__ csr_pos, int* __restrict__ csr_src,
                       int* __restrict__ csr_eid){
  int e = blockIdx.x*256 + threadIdx.x;
  if(e < E){
    int p = atomicAdd(&csr_pos[dst[e]], 1);
    csr_src[p] = src[e];
    csr_eid[p] = e;
  }
}

// ---------------- time embedding + MLP -> cond ----------------
__global__ __launch_bounds__(256) void k_cond(const float* __restrict__ t,
        const float* __restrict__ w1, const float* __restrict__ b1,
        const float* __restrict__ w2, const float* __restrict__ b2,
        float* __restrict__ cond){
  __shared__ float emb[128];
  __shared__ float hid[256];
  int b = blockIdx.x, tid = threadIdx.x;
  float tv = t[b] * 1000.f;
  if(tid < 128){
    int k = tid & 63;
    float fr = expf(-logf(1000.f) * (float)k * (1.f/64.f));
    float a = tv * fr;
    emb[tid] = (tid < 64) ? sinf(a) : cosf(a);
  }
  __syncthreads();
  {
    float s = b1[tid];
    for(int k=0;k<128;k++) s += emb[k] * w1[k*HDIM + tid];
    hid[tid] = silu_(s);
  }
  __syncthreads();
  {
    float s = b2[tid];
    for(int k=0;k<256;k++) s += hid[k] * w2[k*HDIM + tid];
    cond[(size_t)b*HDIM + tid] = s;
  }
}

// ---------------- generic f32 tiled GEMM: 64 rows x 256 cols per block ----------------
template<int K>
__global__ __launch_bounds__(256) void k_gemm_f32(
    const float* __restrict__ A, int lda,
    const float* __restrict__ W, int ldw,
    const float* __restrict__ bias,
    float* __restrict__ out, int ldo, int M, int mode,
    unsigned short* __restrict__ out_bf){
  if(mode == 1){
    int c = blockIdx.y;
    W    += (size_t)(c>>1)*131072 + (size_t)(c&1)*256;
    bias += (size_t)(c>>1)*512 + (size_t)(c&1)*256;
    out  += (size_t)c*1024*256;
  }
  __shared__ float As[64][36];
  __shared__ float Ws[32][256];
  const int tid = threadIdx.x;
  const int rg = tid >> 4;
  const int cg = tid & 15;
  const int row0 = blockIdx.x * 64;

  float4 acc[4][4];
  #pragma unroll
  for(int i=0;i<4;i++)
    #pragma unroll
    for(int m=0;m<4;m++) acc[i][m] = make_float4(0.f,0.f,0.f,0.f);

  const int ar = tid >> 2;
  const int ac = (tid & 3) * 8;
  const int wr = tid >> 3;
  const int wc = (tid & 7) * 32;

  for(int kk=0; kk<K; kk+=32){
    {
      int gr = row0 + ar;
      float4 v0 = make_float4(0.f,0.f,0.f,0.f), v1 = v0;
      if(gr < M){
        v0 = *(const float4*)&A[(size_t)gr*lda + kk + ac];
        v1 = *(const float4*)&A[(size_t)gr*lda + kk + ac + 4];
      }
      *(float4*)&As[ar][ac]   = v0;
      *(float4*)&As[ar][ac+4] = v1;
    }
    #pragma unroll
    for(int u=0;u<8;u++)
      *(float4*)&Ws[wr][wc + u*4] = *(const float4*)&W[(size_t)(kk+wr)*ldw + wc + u*4];
    __syncthreads();
    #pragma unroll 8
    for(int k=0;k<32;k++){
      float a0 = As[rg*4+0][k];
      float a1 = As[rg*4+1][k];
      float a2 = As[rg*4+2][k];
      float a3 = As[rg*4+3][k];
      #pragma unroll
      for(int m=0;m<4;m++){
        float4 w = *(const float4*)&Ws[k][cg*4 + m*64];
        acc[0][m].x += a0*w.x; acc[0][m].y += a0*w.y; acc[0][m].z += a0*w.z; acc[0][m].w += a0*w.w;
        acc[1][m].x += a1*w.x; acc[1][m].y += a1*w.y; acc[1][m].z += a1*w.z; acc[1][m].w += a1*w.w;
        acc[2][m].x += a2*w.x; acc[2][m].y += a2*w.y; acc[2][m].z += a2*w.z; acc[2][m].w += a2*w.w;
        acc[3][m].x += a3*w.x; acc[3][m].y += a3*w.y; acc[3][m].z += a3*w.z; acc[3][m].w += a3*w.w;
      }
    }
    __syncthreads();
  }

  const int c0 = cg * 4;
  #pragma unroll
  for(int i=0;i<4;i++){
    const int gr = row0 + rg*4 + i;
    if(gr >= M) continue;
    #pragma unroll
    for(int m=0;m<4;m++){
      const int c = c0 + m*64;
      float4 b4 = *(const float4*)&bias[c];
      float4 o = make_float4(acc[i][m].x+b4.x, acc[i][m].y+b4.y,
                             acc[i][m].z+b4.z, acc[i][m].w+b4.w);
      if(out) *(float4*)&out[(size_t)gr*ldo + c] = o;
      if(out_bf)
        *(ushort4*)&out_bf[(size_t)gr*ldo + c] =
            make_ushort4(f2bf(o.x), f2bf(o.y), f2bf(o.z), f2bf(o.w));
    }
  }
}

// ---------------- build stacked init weight [64][256] ----------------
__global__ void k_wcat(const float* __restrict__ in_w, const float* __restrict__ ew,
                       const float* __restrict__ eb, float* __restrict__ wcat){
  int idx = blockIdx.x*256 + threadIdx.x;
  int r = idx>>8, c = idx&255;
  float v = 0.f;
  if(r < 32) v = in_w[r*HDIM + c];
  else if(r < 48) v = ew[(r-32)*HDIM + c];
  else if(r == 48) v = eb[c];
  wcat[idx] = v;
}

// ---------------- prepack conv2_w: transpose + bf16 hi/lo split ----------------
__global__ void k_w2b(const float* __restrict__ W, unsigned short* __restrict__ hi_,
                      unsigned short* __restrict__ lo_){
  int idx = blockIdx.x*256 + threadIdx.x;   // 6*65536
  int i = idx >> 16, r = idx & 65535;
  int n = r >> 8, k = r & 255;
  float v = W[((size_t)i*256 + k)*256 + n];
  unsigned short h = f2bf(v);
  float lo = v - bf2f(h);
  hi_[((size_t)i*256 + n)*256 + k] = h;
  lo_[((size_t)i*256 + n)*256 + k] = f2bf(lo);
}

// ---------------- init aggregation ----------------
__global__ __launch_bounds__(256) void k_init_agg(const float* __restrict__ node_x,
    const float* __restrict__ edge_e,
    const int* __restrict__ csr_off, const int* __restrict__ csr_src, const int* __restrict__ csr_eid,
    const float* __restrict__ no, const float* __restrict__ ni, const int* __restrict__ cnt_in,
    float* __restrict__ A48, int N){
  int v = blockIdx.x*4 + (threadIdx.x>>6);
  if(v >= N) return;
  int lane = threadIdx.x & 63;
  int beg = csr_off[v], end = csr_off[v+1];
  float acc = 0.f;
  for(int p=beg; p<end; p++){
    int s = csr_src[p]; int e = csr_eid[p];
    if(lane < 32)      acc += node_x[(size_t)s*32 + lane] * no[s];
    else if(lane < 48) acc += edge_e[(size_t)e*16 + (lane-32)];
  }
  int ci = cnt_in[v];
  float out;
  if(lane < 32)      out = acc * ni[v];
  else if(lane < 48) out = acc * (1.f/(float)max(ci,1));
  else if(lane == 48) out = (ci>0) ? 1.f : 0.f;
  else out = 0.f;
  A48[(size_t)v*64 + lane] = out;
}

// ---------------- per-layer gather: 4 rows per wave (interleaved walks), bf16 h -> bf16 agg ----------------
__global__ __launch_bounds__(256) void k_gather_bf(const unsigned short* __restrict__ hbf,
   const int* __restrict__ csr_off, const int* __restrict__ csr_src,
   const float* __restrict__ no, const float* __restrict__ ni,
   unsigned short* __restrict__ ahi, int N, int Npad){
  const int wid = blockIdx.x*4 + (threadIdx.x>>6);
  const int v0 = wid*4;
  if(v0 >= Npad) return;
  const int lane = threadIdx.x & 63;

  float4 acc[4];
  int p[4], e[4];
  #pragma unroll
  for(int j=0;j<4;j++){
    acc[j] = make_float4(0.f,0.f,0.f,0.f);
    const int v = v0 + j;
    p[j] = (v < N) ? csr_off[v]   : 0;
    e[j] = (v < N) ? csr_off[v+1] : 0;
  }
  for(;;){
    bool a0 = p[0]<e[0], a1 = p[1]<e[1], a2 = p[2]<e[2], a3 = p[3]<e[3];
    if(!(a0|a1|a2|a3)) break;
    int s0=0,s1=0,s2=0,s3=0;
    if(a0) s0 = csr_src[p[0]];
    if(a1) s1 = csr_src[p[1]];
    if(a2) s2 = csr_src[p[2]];
    if(a3) s3 = csr_src[p[3]];
    ushort4 x0,x1,x2,x3;
    if(a0) x0 = *(const ushort4*)&hbf[(size_t)s0*HDIM + lane*4];
    if(a1) x1 = *(const ushort4*)&hbf[(size_t)s1*HDIM + lane*4];
    if(a2) x2 = *(const ushort4*)&hbf[(size_t)s2*HDIM + lane*4];
    if(a3) x3 = *(const ushort4*)&hbf[(size_t)s3*HDIM + lane*4];
    if(a0){ float w=no[s0]; acc[0].x+=bf2f(x0.x)*w; acc[0].y+=bf2f(x0.y)*w; acc[0].z+=bf2f(x0.z)*w; acc[0].w+=bf2f(x0.w)*w; p[0]++; }
    if(a1){ float w=no[s1]; acc[1].x+=bf2f(x1.x)*w; acc[1].y+=bf2f(x1.y)*w; acc[1].z+=bf2f(x1.z)*w; acc[1].w+=bf2f(x1.w)*w; p[1]++; }
    if(a2){ float w=no[s2]; acc[2].x+=bf2f(x2.x)*w; acc[2].y+=bf2f(x2.y)*w; acc[2].z+=bf2f(x2.z)*w; acc[2].w+=bf2f(x2.w)*w; p[2]++; }
    if(a3){ float w=no[s3]; acc[3].x+=bf2f(x3.x)*w; acc[3].y+=bf2f(x3.y)*w; acc[3].z+=bf2f(x3.z)*w; acc[3].w+=bf2f(x3.w)*w; p[3]++; }
  }
  #pragma unroll
  for(int j=0;j<4;j++){
    const int v = v0 + j;
    if(v >= Npad) break;
    float4 a = acc[j];
    if(v < N){
      const float sc = ni[v];
      a.x*=sc; a.y*=sc; a.z*=sc; a.w*=sc;
    }
    *(ushort4*)&ahi[(size_t)v*HDIM + lane*4] =
        make_ushort4(f2bf(a.x), f2bf(a.y), f2bf(a.z), f2bf(a.w));
  }
}

// ---------------- layer GEMM (R13-exact): 4-rows-per-iter epilogue, 40KB -> 4 blocks/CU ----------------
template<bool LAST>
__global__ __launch_bounds__(256) void k_layer_mfma(
    const unsigned short* __restrict__ Ahi,
    const unsigned short* __restrict__ Bhi, const unsigned short* __restrict__ Blo,
    const float* __restrict__ bias, const float* __restrict__ lng, const float* __restrict__ lnb,
    const float* __restrict__ gamL, const float* __restrict__ betL,
    const int* __restrict__ n_index, unsigned short* __restrict__ hbf,
    const float* __restrict__ hw, float* __restrict__ gsum, int N){
  __shared__ __align__(16) char smem[40960];   // 32KB used; padded to 40KB -> 4 blocks/CU
  float* zbuf = (float*)smem;
  const int tid = threadIdx.x;
  const int w = tid >> 6, l = tid & 63;
  const int half = l >> 5, lcol = l & 31;
  const int row0 = blockIdx.x * 64;
  const int colb = w * 64;

  const size_t bb = (size_t)(colb + lcol)*HDIM + half*8;

  short8v Bh0[4], Bh1[4], Bl0[4], Bl1[4];
  #define LOADB(t, s) { \
    Bh0[s] = *(const short8v*)&Bhi[bb + (t)*16]; \
    Bh1[s] = *(const short8v*)&Bhi[bb + 32*HDIM + (t)*16]; \
    Bl0[s] = *(const short8v*)&Blo[bb + (t)*16]; \
    Bl1[s] = *(const short8v*)&Blo[bb + 32*HDIM + (t)*16]; }
  LOADB(0,0) LOADB(1,1) LOADB(2,2)

  {
    const int m = tid & 31;
    const int rofs = tid >> 5;
    #pragma unroll
    for(int chunk=0; chunk<8; chunk++){
      const int row = chunk*8 + rofs;
      const int msw = (m & 24) | ((m ^ row) & 7);
      const size_t src = (size_t)(row0 + row)*HDIM + msw*8;
      gload_lds16(&Ahi[src], (char*)smem + chunk*4096 + tid*16);
    }
  }
  __syncthreads();

  f32x16 acc[2][2] = {};
  const char* baseH = (const char*)smem;

  #pragma unroll
  for(int t=0; t<16; t++){
    if(t < 13) LOADB(t+3, (t+3)&3)
    const int s = t & 3;
    const int g = t*2 + half;
    const int slot = (g & 24) | ((g ^ lcol) & 7);
    short8v ah0 = *(const short8v*)(baseH + lcol*512 + slot*16);
    short8v ah1 = *(const short8v*)(baseH + (32+lcol)*512 + slot*16);

    acc[0][0] = __builtin_amdgcn_mfma_f32_32x32x16_bf16(ah0, Bh0[s], acc[0][0], 0,0,0);
    acc[0][1] = __builtin_amdgcn_mfma_f32_32x32x16_bf16(ah0, Bh1[s], acc[0][1], 0,0,0);
    acc[1][0] = __builtin_amdgcn_mfma_f32_32x32x16_bf16(ah1, Bh0[s], acc[1][0], 0,0,0);
    acc[1][1] = __builtin_amdgcn_mfma_f32_32x32x16_bf16(ah1, Bh1[s], acc[1][1], 0,0,0);
    acc[0][0] = __builtin_amdgcn_mfma_f32_32x32x16_bf16(ah0, Bl0[s], acc[0][0], 0,0,0);
    acc[0][1] = __builtin_amdgcn_mfma_f32_32x32x16_bf16(ah0, Bl1[s], acc[0][1], 0,0,0);
    acc[1][0] = __builtin_amdgcn_mfma_f32_32x32x16_bf16(ah1, Bl0[s], acc[1][0], 0,0,0);
    acc[1][1] = __builtin_amdgcn_mfma_f32_32x32x16_bf16(ah1, Bl1[s], acc[1][1], 0,0,0);
  }
  #undef LOADB

  float bias_c[2];
  bias_c[0] = bias[colb + lcol];
  bias_c[1] = bias[colb + 32 + lcol];

  const int qr = l >> 4, lc = l & 15;
  float4 lngc[4], lnbc[4], hwc[4];
  #pragma unroll
  for(int j=0;j<4;j++){
    lngc[j] = *(const float4*)&lng[lc*4 + j*64];
    lnbc[j] = *(const float4*)&lnb[lc*4 + j*64];
    if(LAST) hwc[j] = *(const float4*)&hw[lc*4 + j*64];
  }

  #pragma unroll
  for(int pass=0; pass<2; pass++){
    __syncthreads();
    #pragma unroll
    for(int r=0; r<16; r++){
      const int rl = (r&3) + 8*(r>>2) + 4*half;
      zbuf[rl*HDIM + colb      + lcol] = acc[pass][0][r] + bias_c[0];
      zbuf[rl*HDIM + colb + 32 + lcol] = acc[pass][1][r] + bias_c[1];
    }
    __syncthreads();
    #pragma unroll
    for(int it=0; it<2; it++){
      const int row = w*8 + it*4 + qr;
      const int grow = row0 + pass*32 + row;
      const bool ok = grow < N;
      const int bidx = ok ? n_index[grow] : 0;
      float4 z[4];
      #pragma unroll
      for(int j=0;j<4;j++) z[j] = *(const float4*)&zbuf[row*HDIM + lc*4 + j*64];
      float s = 0.f, q = 0.f;
      #pragma unroll
      for(int j=0;j<4;j++){
        s += z[j].x + z[j].y + z[j].z + z[j].w;
        q += z[j].x*z[j].x + z[j].y*z[j].y + z[j].z*z[j].z + z[j].w*z[j].w;
      }
      #pragma unroll
      for(int off=1; off<16; off<<=1){ s += __shfl_xor(s, off, 16); q += __shfl_xor(q, off, 16); }
      const float mu = s * (1.f/256.f);
      const float rs = rsqrtf(fmaxf(q*(1.f/256.f) - mu*mu, 0.f) + 1e-5f);
      float4 g4[4], b4[4];
      #pragma unroll
      for(int j=0;j<4;j++){
        g4[j] = *(const float4*)&gamL[(size_t)bidx*HDIM + lc*4 + j*64];
        b4[j] = *(const float4*)&betL[(size_t)bidx*HDIM + lc*4 + j*64];
      }
      float4 o[4];
      #pragma unroll
      for(int j=0;j<4;j++){
        float zn;
        zn = (z[j].x-mu)*rs*lngc[j].x + lnbc[j].x; o[j].x = silu_(zn*(1.f+g4[j].x)+b4[j].x);
        zn = (z[j].y-mu)*rs*lngc[j].y + lnbc[j].y; o[j].y = silu_(zn*(1.f+g4[j].y)+b4[j].y);
        zn = (z[j].z-mu)*rs*lngc[j].z + lnbc[j].z; o[j].z = silu_(zn*(1.f+g4[j].z)+b4[j].z);
        zn = (z[j].w-mu)*rs*lngc[j].w + lnbc[j].w; o[j].w = silu_(zn*(1.f+g4[j].w)+b4[j].w);
      }
      if(LAST){
        float rd = 0.f;
        #pragma unroll
        for(int j=0;j<4;j++){
          ushort4 hv = ok ? *(const ushort4*)&hbf[(size_t)grow*HDIM + lc*4 + j*64]
                          : make_ushort4(0,0,0,0);
          rd += (o[j].x+bf2f(hv.x))*hwc[j].x + (o[j].y+bf2f(hv.y))*hwc[j].y
              + (o[j].z+bf2f(hv.z))*hwc[j].z + (o[j].w+bf2f(hv.w))*hwc[j].w;
        }
        #pragma unroll
        for(int off=1; off<16; off<<=1) rd += __shfl_xor(rd, off, 16);
        if(lc == 0 && ok) atomicAdd(&gsum[bidx], rd);
      } else {
        if(ok){
          #pragma unroll
          for(int j=0;j<4;j++){
            ushort4 hv = *(const ushort4*)&hbf[(size_t)grow*HDIM + lc*4 + j*64];
            float ox = o[j].x + bf2f(hv.x), oy = o[j].y + bf2f(hv.y);
            float oz = o[j].z + bf2f(hv.z), ow = o[j].w + bf2f(hv.w);
            *(ushort4*)&hbf[(size_t)grow*HDIM + lc*4 + j*64] =
                make_ushort4(f2bf(ox), f2bf(oy), f2bf(oz), f2bf(ow));
          }
        }
      }
    }
  }
}

__global__ void k_final(const float* __restrict__ gsum, const int* __restrict__ gcnt,
                        const float* __restrict__ hb, float* __restrict__ out, int B){
  int b = blockIdx.x*256 + threadIdx.x;
  if(b < B) out[b] = gsum[b] / (float)max(gcnt[b],1) + hb[0];
}

extern "C" void kernel_launch(void* const* d_in, const int* in_sizes, int n_in,
                              void* d_out, int out_size, void* d_ws, size_t ws_size,
                              hipStream_t stream){
  const float* node_x   = (const float*)d_in[0];
  const float* edge_e   = (const float*)d_in[1];
  const float* t        = (const float*)d_in[2];
  const int*   n_index  = (const int*)d_in[3];
  const int*   src      = (const int*)d_in[4];
  const int*   dst      = (const int*)d_in[5];
  const float* in_conv_w= (const float*)d_in[6];
  const float* in_conv_b= (const float*)d_in[7];
  const float* edge_w   = (const float*)d_in[8];
  const float* edge_b   = (const float*)d_in[9];
  const float* t_w1     = (const float*)d_in[10];
  const float* t_b1     = (const float*)d_in[11];
  const float* t_w2     = (const float*)d_in[12];
  const float* t_b2     = (const float*)d_in[13];
  const float* conv2_w  = (const float*)d_in[16];
  const float* conv2_b  = (const float*)d_in[17];
  const float* ln2_g    = (const float*)d_in[20];
  const float* ln2_b    = (const float*)d_in[21];
  const float* film2_w  = (const float*)d_in[24];
  const float* film2_b  = (const float*)d_in[25];
  const float* head_w   = (const float*)d_in[26];
  const float* head_b   = (const float*)d_in[27];

  const int N = in_sizes[3];
  const int E = in_sizes[4];
  const int B = in_sizes[2];
  const int Npad = (N + 63) & ~63;

  char* w = (char*)d_ws;
  auto alloc = [&](size_t bytes)->char*{
    char* p = w; w += (bytes + 255) & ~(size_t)255; return p;
  };
  int*   cnt_out = (int*)  alloc((size_t)N*4);
  int*   cnt_in  = (int*)  alloc((size_t)N*4);
  float* no      = (float*)alloc((size_t)N*4);
  float* ni      = (float*)alloc((size_t)N*4);
  int*   csr_off = (int*)  alloc((size_t)(N+1)*4);
  int*   csr_pos = (int*)  alloc((size_t)N*4);
  int*   csr_src = (int*)  alloc((size_t)E*4);
  int*   csr_eid = (int*)  alloc((size_t)E*4);
  int*   partial = (int*)  alloc((size_t)256*4);
  float* cond    = (float*)alloc((size_t)B*HDIM*4);
  float* gbX     = (float*)alloc((size_t)12*B*HDIM*4);
  float* gsum    = (float*)alloc((size_t)B*4);
  int*   gcnt    = (int*)  alloc((size_t)B*4);
  unsigned short* hbf    = (unsigned short*)alloc((size_t)Npad*HDIM*2);
  unsigned short* agg_hi = (unsigned short*)alloc((size_t)Npad*HDIM*2);
  unsigned short* Wthi   = (unsigned short*)alloc((size_t)NLAYERS*HDIM*HDIM*2);
  unsigned short* Wtlo   = (unsigned short*)alloc((size_t)NLAYERS*HDIM*HDIM*2);
  float* wcat    = (float*)alloc((size_t)64*HDIM*4);
  float* A48     = (float*)alloc((size_t)Npad*64*4);

  hipMemsetAsync(cnt_out, 0, (size_t)N*4, stream);
  hipMemsetAsync(cnt_in,  0, (size_t)N*4, stream);
  hipMemsetAsync(gsum,    0, (size_t)B*4, stream);
  hipMemsetAsync(gcnt,    0, (size_t)B*4, stream);

  int gE = (E+255)/256, gN = (N+255)/256;
  int nb1 = (N+1023)/1024;
  k_count<<<gE,256,0,stream>>>(src, dst, E, cnt_out, cnt_in);
  k_scan1<<<nb1,256,0,stream>>>(cnt_in, partial, N);
  k_scan2<<<1,256,0,stream>>>(partial, csr_off, nb1, N);
  k_scan3<<<nb1,256,0,stream>>>(cnt_in, partial, csr_off, N);
  k_prep<<<gN,256,0,stream>>>(cnt_out, cnt_in, csr_off, n_index, no, ni, csr_pos, gcnt, N);
  k_fill<<<gE,256,0,stream>>>(src, dst, E, csr_pos, csr_src, csr_eid);

  k_cond<<<B,256,0,stream>>>(t, t_w1, t_b1, t_w2, t_b2, cond);
  k_gemm_f32<256><<<dim3(B/64,12),256,0,stream>>>(cond, HDIM, film2_w, 512, film2_b,
                                                  gbX, HDIM, B, 1, nullptr);

  k_w2b<<<NLAYERS*HDIM*HDIM/256,256,0,stream>>>(conv2_w, Wthi, Wtlo);
  k_wcat<<<64,256,0,stream>>>(in_conv_w, edge_w, edge_b, wcat);
  k_init_agg<<<(N+3)/4,256,0,stream>>>(node_x, edge_e, csr_off, csr_src, csr_eid,
                                       no, ni, cnt_in, A48, N);
  k_gemm_f32<64><<<Npad/64,256,0,stream>>>(A48, 64, wcat, HDIM, in_conv_b,
                                           nullptr, HDIM, N, 0, hbf);

  for(int i=0;i<NLAYERS;i++){
    k_gather_bf<<<Npad/16,256,0,stream>>>(hbf, csr_off, csr_src, no, ni, agg_hi, N, Npad);
    if(i < NLAYERS-1)
      k_layer_mfma<false><<<Npad/64,256,0,stream>>>(agg_hi,
          Wthi + (size_t)i*HDIM*HDIM, Wtlo + (size_t)i*HDIM*HDIM,
          conv2_b + (size_t)i*HDIM,
          ln2_g + (size_t)i*HDIM, ln2_b + (size_t)i*HDIM,
          gbX + (size_t)(2*i)*B*HDIM, gbX + (size_t)(2*i+1)*B*HDIM,
          n_index, hbf, head_w, gsum, N);
    else
      k_layer_mfma<true><<<Npad/64,256,0,stream>>>(agg_hi,
          Wthi + (size_t)i*HDIM*HDIM, Wtlo + (size_t)i*HDIM*HDIM,
          conv2_b + (size_t)i*HDIM,
          ln2_g + (size_t)i*HDIM, ln2_b + (size_t)i*HDIM,
          gbX + (size_t)(2*i)*B*HDIM, gbX + (size_t)(2*i+1)*B*HDIM,
          n_index, hbf, head_w, gsum, N);
  }

  k_final<<<(B+255)/256,256,0,stream>>>(gsum, gcnt, head_b, (float*)d_out, B);
}

// Round 19
// 1290.936 us; speedup vs baseline: 1.3385x; 1.0867x over previous
//
#include <hip/hip_runtime.h>
#include <math.h>

#define HDIM 256
#define NLAYERS 6

typedef __attribute__((ext_vector_type(8))) short short8v;
typedef __attribute__((ext_vector_type(16))) float f32x16;

__device__ __forceinline__ float silu_(float x){ return x * (1.f/(1.f+__expf(-x))); }

__device__ __forceinline__ unsigned short f2bf(float f){
  unsigned u = __float_as_uint(f);
  u += 0x7FFF + ((u>>16)&1);
  return (unsigned short)(u>>16);
}
__device__ __forceinline__ float bf2f(unsigned short b){ return __uint_as_float(((unsigned)b)<<16); }

__device__ __forceinline__ void gload_lds16(const void* g, void* l){
  __builtin_amdgcn_global_load_lds((const __attribute__((address_space(1))) void*)g,
                                   (__attribute__((address_space(3))) void*)l, 16, 0, 0);
}

// ---------------- degree counting ----------------
__global__ void k_count(const int* __restrict__ src, const int* __restrict__ dst, int E,
                        int* __restrict__ cnt_out, int* __restrict__ cnt_in){
  int e = blockIdx.x*256 + threadIdx.x;
  if(e < E){
    atomicAdd(&cnt_out[src[e]], 1);
    atomicAdd(&cnt_in[dst[e]], 1);
  }
}

// ---------------- multi-block exclusive scan of cnt_in -> csr_off ----------------
__global__ __launch_bounds__(256) void k_scan1(const int* __restrict__ cnt_in,
                                               int* __restrict__ partial, int N){
  __shared__ int s[256];
  int b = blockIdx.x, tid = threadIdx.x;
  int i0 = b*1024 + tid*4;
  int sum = 0;
  #pragma unroll
  for(int j=0;j<4;j++){ int i=i0+j; if(i<N) sum += cnt_in[i]; }
  s[tid] = sum; __syncthreads();
  for(int off=128; off; off>>=1){ if(tid<off) s[tid]+=s[tid+off]; __syncthreads(); }
  if(tid==0) partial[b] = s[0];
}
__global__ __launch_bounds__(256) void k_scan2(int* __restrict__ partial,
                                               int* __restrict__ csr_off, int nb, int N){
  __shared__ int s[256];
  int tid = threadIdx.x;
  int v = (tid<nb) ? partial[tid] : 0;
  s[tid] = v; __syncthreads();
  for(int off=1; off<256; off<<=1){
    int t = (tid>=off) ? s[tid-off] : 0;
    __syncthreads(); s[tid] += t; __syncthreads();
  }
  if(tid<nb) partial[tid] = s[tid] - v;
  if(tid==255) csr_off[N] = s[255];
}
__global__ __launch_bounds__(256) void k_scan3(const int* __restrict__ cnt_in,
                                               const int* __restrict__ partial,
                                               int* __restrict__ csr_off, int N){
  __shared__ int s[256];
  int b = blockIdx.x, tid = threadIdx.x;
  int i0 = b*1024 + tid*4;
  int c[4];
  #pragma unroll
  for(int j=0;j<4;j++){ int i=i0+j; c[j] = (i<N) ? cnt_in[i] : 0; }
  int tot = c[0]+c[1]+c[2]+c[3];
  s[tid] = tot; __syncthreads();
  for(int off=1; off<256; off<<=1){
    int t = (tid>=off) ? s[tid-off] : 0;
    __syncthreads(); s[tid] += t; __syncthreads();
  }
  int run = s[tid] - tot + partial[b];
  #pragma unroll
  for(int j=0;j<4;j++){
    int i = i0+j;
    if(i<N) csr_off[i] = run;
    run += c[j];
  }
}

// ---------------- norms + csr fill pointer + per-graph node count ----------------
__global__ void k_prep(const int* __restrict__ cnt_out, const int* __restrict__ cnt_in,
                       const int* __restrict__ csr_off, const int* __restrict__ n_index,
                       float* __restrict__ no, float* __restrict__ ni,
                       int* __restrict__ csr_pos, int* __restrict__ gcnt, int N){
  int v = blockIdx.x*256 + threadIdx.x;
  if(v < N){
    no[v] = rsqrtf((float)max(cnt_out[v],1));
    ni[v] = rsqrtf((float)max(cnt_in[v],1));
    csr_pos[v] = csr_off[v];
    atomicAdd(&gcnt[n_index[v]], 1);
  }
}

__global__ void k_fill(const int* __restrict__ src, const int* __restrict__ dst, int E,
                       int* __restrict__ csr_pos, int* __restrict__ csr_src,
                       int* __restrict__ csr_eid){
  int e = blockIdx.x*256 + threadIdx.x;
  if(e < E){
    int p = atomicAdd(&csr_pos[dst[e]], 1);
    csr_src[p] = src[e];
    csr_eid[p] = e;
  }
}

// ---------------- time embedding + MLP -> cond ----------------
__global__ __launch_bounds__(256) void k_cond(const float* __restrict__ t,
        const float* __restrict__ w1, const float* __restrict__ b1,
        const float* __restrict__ w2, const float* __restrict__ b2,
        float* __restrict__ cond){
  __shared__ float emb[128];
  __shared__ float hid[256];
  int b = blockIdx.x, tid = threadIdx.x;
  float tv = t[b] * 1000.f;
  if(tid < 128){
    int k = tid & 63;
    float fr = expf(-logf(1000.f) * (float)k * (1.f/64.f));
    float a = tv * fr;
    emb[tid] = (tid < 64) ? sinf(a) : cosf(a);
  }
  __syncthreads();
  {
    float s = b1[tid];
    for(int k=0;k<128;k++) s += emb[k] * w1[k*HDIM + tid];
    hid[tid] = silu_(s);
  }
  __syncthreads();
  {
    float s = b2[tid];
    for(int k=0;k<256;k++) s += hid[k] * w2[k*HDIM + tid];
    cond[(size_t)b*HDIM + tid] = s;
  }
}

// ---------------- generic f32 tiled GEMM: 64 rows x 256 cols per block ----------------
template<int K>
__global__ __launch_bounds__(256) void k_gemm_f32(
    const float* __restrict__ A, int lda,
    const float* __restrict__ W, int ldw,
    const float* __restrict__ bias,
    float* __restrict__ out, int ldo, int M, int mode,
    unsigned short* __restrict__ out_bf){
  if(mode == 1){
    int c = blockIdx.y;
    W    += (size_t)(c>>1)*131072 + (size_t)(c&1)*256;
    bias += (size_t)(c>>1)*512 + (size_t)(c&1)*256;
    out  += (size_t)c*1024*256;
  }
  __shared__ float As[64][36];
  __shared__ float Ws[32][256];
  const int tid = threadIdx.x;
  const int rg = tid >> 4;
  const int cg = tid & 15;
  const int row0 = blockIdx.x * 64;

  float4 acc[4][4];
  #pragma unroll
  for(int i=0;i<4;i++)
    #pragma unroll
    for(int m=0;m<4;m++) acc[i][m] = make_float4(0.f,0.f,0.f,0.f);

  const int ar = tid >> 2;
  const int ac = (tid & 3) * 8;
  const int wr = tid >> 3;
  const int wc = (tid & 7) * 32;

  for(int kk=0; kk<K; kk+=32){
    {
      int gr = row0 + ar;
      float4 v0 = make_float4(0.f,0.f,0.f,0.f), v1 = v0;
      if(gr < M){
        v0 = *(const float4*)&A[(size_t)gr*lda + kk + ac];
        v1 = *(const float4*)&A[(size_t)gr*lda + kk + ac + 4];
      }
      *(float4*)&As[ar][ac]   = v0;
      *(float4*)&As[ar][ac+4] = v1;
    }
    #pragma unroll
    for(int u=0;u<8;u++)
      *(float4*)&Ws[wr][wc + u*4] = *(const float4*)&W[(size_t)(kk+wr)*ldw + wc + u*4];
    __syncthreads();
    #pragma unroll 8
    for(int k=0;k<32;k++){
      float a0 = As[rg*4+0][k];
      float a1 = As[rg*4+1][k];
      float a2 = As[rg*4+2][k];
      float a3 = As[rg*4+3][k];
      #pragma unroll
      for(int m=0;m<4;m++){
        float4 w = *(const float4*)&Ws[k][cg*4 + m*64];
        acc[0][m].x += a0*w.x; acc[0][m].y += a0*w.y; acc[0][m].z += a0*w.z; acc[0][m].w += a0*w.w;
        acc[1][m].x += a1*w.x; acc[1][m].y += a1*w.y; acc[1][m].z += a1*w.z; acc[1][m].w += a1*w.w;
        acc[2][m].x += a2*w.x; acc[2][m].y += a2*w.y; acc[2][m].z += a2*w.z; acc[2][m].w += a2*w.w;
        acc[3][m].x += a3*w.x; acc[3][m].y += a3*w.y; acc[3][m].z += a3*w.z; acc[3][m].w += a3*w.w;
      }
    }
    __syncthreads();
  }

  const int c0 = cg * 4;
  #pragma unroll
  for(int i=0;i<4;i++){
    const int gr = row0 + rg*4 + i;
    if(gr >= M) continue;
    #pragma unroll
    for(int m=0;m<4;m++){
      const int c = c0 + m*64;
      float4 b4 = *(const float4*)&bias[c];
      float4 o = make_float4(acc[i][m].x+b4.x, acc[i][m].y+b4.y,
                             acc[i][m].z+b4.z, acc[i][m].w+b4.w);
      if(out) *(float4*)&out[(size_t)gr*ldo + c] = o;
      if(out_bf)
        *(ushort4*)&out_bf[(size_t)gr*ldo + c] =
            make_ushort4(f2bf(o.x), f2bf(o.y), f2bf(o.z), f2bf(o.w));
    }
  }
}

// ---------------- build stacked init weight [64][256] ----------------
__global__ void k_wcat(const float* __restrict__ in_w, const float* __restrict__ ew,
                       const float* __restrict__ eb, float* __restrict__ wcat){
  int idx = blockIdx.x*256 + threadIdx.x;
  int r = idx>>8, c = idx&255;
  float v = 0.f;
  if(r < 32) v = in_w[r*HDIM + c];
  else if(r < 48) v = ew[(r-32)*HDIM + c];
  else if(r == 48) v = eb[c];
  wcat[idx] = v;
}

// ---------------- prepack conv2_w: transpose + bf16 hi/lo split ----------------
__global__ void k_w2b(const float* __restrict__ W, unsigned short* __restrict__ hi_,
                      unsigned short* __restrict__ lo_){
  int idx = blockIdx.x*256 + threadIdx.x;   // 6*65536
  int i = idx >> 16, r = idx & 65535;
  int n = r >> 8, k = r & 255;
  float v = W[((size_t)i*256 + k)*256 + n];
  unsigned short h = f2bf(v);
  float lo = v - bf2f(h);
  hi_[((size_t)i*256 + n)*256 + k] = h;
  lo_[((size_t)i*256 + n)*256 + k] = f2bf(lo);
}

// ---------------- init aggregation ----------------
__global__ __launch_bounds__(256) void k_init_agg(const float* __restrict__ node_x,
    const float* __restrict__ edge_e,
    const int* __restrict__ csr_off, const int* __restrict__ csr_src, const int* __restrict__ csr_eid,
    const float* __restrict__ no, const float* __restrict__ ni, const int* __restrict__ cnt_in,
    float* __restrict__ A48, int N){
  int v = blockIdx.x*4 + (threadIdx.x>>6);
  if(v >= N) return;
  int lane = threadIdx.x & 63;
  int beg = csr_off[v], end = csr_off[v+1];
  float acc = 0.f;
  for(int p=beg; p<end; p++){
    int s = csr_src[p]; int e = csr_eid[p];
    if(lane < 32)      acc += node_x[(size_t)s*32 + lane] * no[s];
    else if(lane < 48) acc += edge_e[(size_t)e*16 + (lane-32)];
  }
  int ci = cnt_in[v];
  float out;
  if(lane < 32)      out = acc * ni[v];
  else if(lane < 48) out = acc * (1.f/(float)max(ci,1));
  else if(lane == 48) out = (ci>0) ? 1.f : 0.f;
  else out = 0.f;
  A48[(size_t)v*64 + lane] = out;
}

// ---------------- per-layer gather: XCD-aligned block remap, bf16 h -> bf16 agg ----------------
__global__ __launch_bounds__(256) void k_gather_bf(const unsigned short* __restrict__ hbf,
   const int* __restrict__ csr_off, const int* __restrict__ csr_src,
   const float* __restrict__ no, const float* __restrict__ ni,
   unsigned short* __restrict__ ahi, int N, int Npad, int fullTiles){
  int i = blockIdx.x;
  int tile, s;
  if(i < fullTiles*16){
    int chunk = i >> 7;          // group of 128 blocks = 8 tiles
    int r = i & 127;
    int x = r & 7;               // XCD slot == tile%8
    s = r >> 3;                  // 0..15 sub-block within tile
    tile = chunk*8 + x;
  } else {
    int rem = i - fullTiles*16;
    tile = fullTiles + (rem >> 4);
    s = rem & 15;
  }
  int v = tile*64 + s*4 + (threadIdx.x>>6);
  if(v >= Npad) return;
  int lane = threadIdx.x & 63;
  float4 acc = make_float4(0.f,0.f,0.f,0.f);
  if(v < N){
    int beg = csr_off[v], end = csr_off[v+1];
    for(int p=beg; p<end; p++){
      int sN = csr_src[p];
      float w = no[sN];
      ushort4 x4 = *(const ushort4*)&hbf[(size_t)sN*HDIM + lane*4];
      acc.x += bf2f(x4.x)*w; acc.y += bf2f(x4.y)*w;
      acc.z += bf2f(x4.z)*w; acc.w += bf2f(x4.w)*w;
    }
    float sc = ni[v];
    acc.x*=sc; acc.y*=sc; acc.z*=sc; acc.w*=sc;
  }
  ushort4 hv = make_ushort4(f2bf(acc.x), f2bf(acc.y), f2bf(acc.z), f2bf(acc.w));
  *(ushort4*)&ahi[(size_t)v*HDIM + lane*4] = hv;
}

// ---------------- layer GEMM: 4-rows-per-iter epilogue (16 lanes/row, 4x MLP) ----------------
// block = 256 thr = 4 waves; tile 64 rows x 256 cols; wave tile 64x64 (2x2 of 32x32)
// LDS padded to 40KB -> exactly 4 blocks/CU (5 blocks/CU empirically thrashes L2->HBM writes).
template<bool LAST>
__global__ __launch_bounds__(256) void k_layer_mfma(
    const unsigned short* __restrict__ Ahi,
    const unsigned short* __restrict__ Bhi, const unsigned short* __restrict__ Blo,
    const float* __restrict__ bias, const float* __restrict__ lng, const float* __restrict__ lnb,
    const float* __restrict__ gamL, const float* __restrict__ betL,
    const int* __restrict__ n_index, unsigned short* __restrict__ hbf,
    const float* __restrict__ hw, float* __restrict__ gsum, int N){
  __shared__ __align__(16) char smem[40960];   // 32KB used; padded to 40KB -> 4 blocks/CU
  float* zbuf = (float*)smem;
  const int tid = threadIdx.x;
  const int w = tid >> 6, l = tid & 63;
  const int half = l >> 5, lcol = l & 31;
  const int row0 = blockIdx.x * 64;
  const int colb = w * 64;

  const size_t bb = (size_t)(colb + lcol)*HDIM + half*8;

  short8v Bh0[4], Bh1[4], Bl0[4], Bl1[4];
  #define LOADB(t, s) { \
    Bh0[s] = *(const short8v*)&Bhi[bb + (t)*16]; \
    Bh1[s] = *(const short8v*)&Bhi[bb + 32*HDIM + (t)*16]; \
    Bl0[s] = *(const short8v*)&Blo[bb + (t)*16]; \
    Bl1[s] = *(const short8v*)&Blo[bb + 32*HDIM + (t)*16]; }
  LOADB(0,0) LOADB(1,1) LOADB(2,2)

  // stage entire A tile (bf16): 8 chunks x (256 thr * 16B) = 32KB, swizzled source
  {
    const int m = tid & 31;          // 16B slot within row
    const int rofs = tid >> 5;       // 0..7
    #pragma unroll
    for(int chunk=0; chunk<8; chunk++){
      const int row = chunk*8 + rofs;
      const int msw = (m & 24) | ((m ^ row) & 7);           // inverse-swizzled source slot
      const size_t src = (size_t)(row0 + row)*HDIM + msw*8;
      gload_lds16(&Ahi[src], (char*)smem + chunk*4096 + tid*16);
    }
  }
  __syncthreads();   // all A staged

  f32x16 acc[2][2] = {};
  const char* baseH = (const char*)smem;

  #pragma unroll
  for(int t=0; t<16; t++){
    if(t < 13) LOADB(t+3, (t+3)&3)
    const int s = t & 3;
    const int g = t*2 + half;                         // global 16B slot in row
    const int slot = (g & 24) | ((g ^ lcol) & 7);     // swizzled LDS slot
    short8v ah0 = *(const short8v*)(baseH + lcol*512 + slot*16);
    short8v ah1 = *(const short8v*)(baseH + (32+lcol)*512 + slot*16);

    acc[0][0] = __builtin_amdgcn_mfma_f32_32x32x16_bf16(ah0, Bh0[s], acc[0][0], 0,0,0);
    acc[0][1] = __builtin_amdgcn_mfma_f32_32x32x16_bf16(ah0, Bh1[s], acc[0][1], 0,0,0);
    acc[1][0] = __builtin_amdgcn_mfma_f32_32x32x16_bf16(ah1, Bh0[s], acc[1][0], 0,0,0);
    acc[1][1] = __builtin_amdgcn_mfma_f32_32x32x16_bf16(ah1, Bh1[s], acc[1][1], 0,0,0);
    acc[0][0] = __builtin_amdgcn_mfma_f32_32x32x16_bf16(ah0, Bl0[s], acc[0][0], 0,0,0);
    acc[0][1] = __builtin_amdgcn_mfma_f32_32x32x16_bf16(ah0, Bl1[s], acc[0][1], 0,0,0);
    acc[1][0] = __builtin_amdgcn_mfma_f32_32x32x16_bf16(ah1, Bl0[s], acc[1][0], 0,0,0);
    acc[1][1] = __builtin_amdgcn_mfma_f32_32x32x16_bf16(ah1, Bl1[s], acc[1][1], 0,0,0);
  }
  #undef LOADB

  // ---- epilogue: 2 passes of 32 rows via aliased 32KB f32 z-buffer ----
  float bias_c[2];
  bias_c[0] = bias[colb + lcol];
  bias_c[1] = bias[colb + 32 + lcol];

  // phase-2 mapping: lane (qr,lc) covers cols lc*4 + 64*j, j=0..3 of its row
  const int qr = l >> 4, lc = l & 15;
  float4 lngc[4], lnbc[4], hwc[4];
  #pragma unroll
  for(int j=0;j<4;j++){
    lngc[j] = *(const float4*)&lng[lc*4 + j*64];
    lnbc[j] = *(const float4*)&lnb[lc*4 + j*64];
    if(LAST) hwc[j] = *(const float4*)&hw[lc*4 + j*64];
  }

  #pragma unroll
  for(int pass=0; pass<2; pass++){
    __syncthreads();   // pass0: A reads done; pass1: previous z reads done
    #pragma unroll
    for(int r=0; r<16; r++){
      const int rl = (r&3) + 8*(r>>2) + 4*half;
      zbuf[rl*HDIM + colb      + lcol] = acc[pass][0][r] + bias_c[0];
      zbuf[rl*HDIM + colb + 32 + lcol] = acc[pass][1][r] + bias_c[1];
    }
    __syncthreads();
    #pragma unroll
    for(int it=0; it<2; it++){
      const int row = w*8 + it*4 + qr;
      const int grow = row0 + pass*32 + row;
      const bool ok = grow < N;
      const int bidx = ok ? n_index[grow] : 0;
      float4 z[4];
      #pragma unroll
      for(int j=0;j<4;j++) z[j] = *(const float4*)&zbuf[row*HDIM + lc*4 + j*64];
      float s = 0.f, q = 0.f;
      #pragma unroll
      for(int j=0;j<4;j++){
        s += z[j].x + z[j].y + z[j].z + z[j].w;
        q += z[j].x*z[j].x + z[j].y*z[j].y + z[j].z*z[j].z + z[j].w*z[j].w;
      }
      #pragma unroll
      for(int off=1; off<16; off<<=1){ s += __shfl_xor(s, off, 16); q += __shfl_xor(q, off, 16); }
      const float mu = s * (1.f/256.f);
      const float rs = rsqrtf(fmaxf(q*(1.f/256.f) - mu*mu, 0.f) + 1e-5f);
      float4 g4[4], b4[4];
      #pragma unroll
      for(int j=0;j<4;j++){
        g4[j] = *(const float4*)&gamL[(size_t)bidx*HDIM + lc*4 + j*64];
        b4[j] = *(const float4*)&betL[(size_t)bidx*HDIM + lc*4 + j*64];
      }
      float4 o[4];
      #pragma unroll
      for(int j=0;j<4;j++){
        float zn;
        zn = (z[j].x-mu)*rs*lngc[j].x + lnbc[j].x; o[j].x = silu_(zn*(1.f+g4[j].x)+b4[j].x);
        zn = (z[j].y-mu)*rs*lngc[j].y + lnbc[j].y; o[j].y = silu_(zn*(1.f+g4[j].y)+b4[j].y);
        zn = (z[j].z-mu)*rs*lngc[j].z + lnbc[j].z; o[j].z = silu_(zn*(1.f+g4[j].z)+b4[j].z);
        zn = (z[j].w-mu)*rs*lngc[j].w + lnbc[j].w; o[j].w = silu_(zn*(1.f+g4[j].w)+b4[j].w);
      }
      if(LAST){
        float rd = 0.f;
        #pragma unroll
        for(int j=0;j<4;j++){
          ushort4 hv = ok ? *(const ushort4*)&hbf[(size_t)grow*HDIM + lc*4 + j*64]
                          : make_ushort4(0,0,0,0);
          rd += (o[j].x+bf2f(hv.x))*hwc[j].x + (o[j].y+bf2f(hv.y))*hwc[j].y
              + (o[j].z+bf2f(hv.z))*hwc[j].z + (o[j].w+bf2f(hv.w))*hwc[j].w;
        }
        #pragma unroll
        for(int off=1; off<16; off<<=1) rd += __shfl_xor(rd, off, 16);
        if(lc == 0 && ok) atomicAdd(&gsum[bidx], rd);
      } else {
        if(ok){
          #pragma unroll
          for(int j=0;j<4;j++){
            ushort4 hv = *(const ushort4*)&hbf[(size_t)grow*HDIM + lc*4 + j*64];
            float ox = o[j].x + bf2f(hv.x), oy = o[j].y + bf2f(hv.y);
            float oz = o[j].z + bf2f(hv.z), ow = o[j].w + bf2f(hv.w);
            *(ushort4*)&hbf[(size_t)grow*HDIM + lc*4 + j*64] =
                make_ushort4(f2bf(ox), f2bf(oy), f2bf(oz), f2bf(ow));
          }
        }
      }
    }
  }
}

__global__ void k_final(const float* __restrict__ gsum, const int* __restrict__ gcnt,
                        const float* __restrict__ hb, float* __restrict__ out, int B){
  int b = blockIdx.x*256 + threadIdx.x;
  if(b < B) out[b] = gsum[b] / (float)max(gcnt[b],1) + hb[0];
}

extern "C" void kernel_launch(void* const* d_in, const int* in_sizes, int n_in,
                              void* d_out, int out_size, void* d_ws, size_t ws_size,
                              hipStream_t stream){
  const float* node_x   = (const float*)d_in[0];
  const float* edge_e   = (const float*)d_in[1];
  const float* t        = (const float*)d_in[2];
  const int*   n_index  = (const int*)d_in[3];
  const int*   src      = (const int*)d_in[4];
  const int*   dst      = (const int*)d_in[5];
  const float* in_conv_w= (const float*)d_in[6];
  const float* in_conv_b= (const float*)d_in[7];
  const float* edge_w   = (const float*)d_in[8];
  const float* edge_b   = (const float*)d_in[9];
  const float* t_w1     = (const float*)d_in[10];
  const float* t_b1     = (const float*)d_in[11];
  const float* t_w2     = (const float*)d_in[12];
  const float* t_b2     = (const float*)d_in[13];
  const float* conv2_w  = (const float*)d_in[16];
  const float* conv2_b  = (const float*)d_in[17];
  const float* ln2_g    = (const float*)d_in[20];
  const float* ln2_b    = (const float*)d_in[21];
  const float* film2_w  = (const float*)d_in[24];
  const float* film2_b  = (const float*)d_in[25];
  const float* head_w   = (const float*)d_in[26];
  const float* head_b   = (const float*)d_in[27];

  const int N = in_sizes[3];
  const int E = in_sizes[4];
  const int B = in_sizes[2];
  const int Npad = (N + 63) & ~63;
  const int nTiles = Npad / 64;
  const int fullTiles = nTiles & ~7;   // XCD-aligned region (multiple of 8 tiles)

  char* w = (char*)d_ws;
  auto alloc = [&](size_t bytes)->char*{
    char* p = w; w += (bytes + 255) & ~(size_t)255; return p;
  };
  int*   cnt_out = (int*)  alloc((size_t)N*4);
  int*   cnt_in  = (int*)  alloc((size_t)N*4);
  float* no      = (float*)alloc((size_t)N*4);
  float* ni      = (float*)alloc((size_t)N*4);
  int*   csr_off = (int*)  alloc((size_t)(N+1)*4);
  int*   csr_pos = (int*)  alloc((size_t)N*4);
  int*   csr_src = (int*)  alloc((size_t)E*4);
  int*   csr_eid = (int*)  alloc((size_t)E*4);
  int*   partial = (int*)  alloc((size_t)256*4);
  float* cond    = (float*)alloc((size_t)B*HDIM*4);
  float* gbX     = (float*)alloc((size_t)12*B*HDIM*4);
  float* gsum    = (float*)alloc((size_t)B*4);
  int*   gcnt    = (int*)  alloc((size_t)B*4);
  unsigned short* hbf    = (unsigned short*)alloc((size_t)Npad*HDIM*2);
  unsigned short* agg_hi = (unsigned short*)alloc((size_t)Npad*HDIM*2);
  unsigned short* Wthi   = (unsigned short*)alloc((size_t)NLAYERS*HDIM*HDIM*2);
  unsigned short* Wtlo   = (unsigned short*)alloc((size_t)NLAYERS*HDIM*HDIM*2);
  float* wcat    = (float*)alloc((size_t)64*HDIM*4);
  float* A48     = (float*)alloc((size_t)Npad*64*4);

  hipMemsetAsync(cnt_out, 0, (size_t)N*4, stream);
  hipMemsetAsync(cnt_in,  0, (size_t)N*4, stream);
  hipMemsetAsync(gsum,    0, (size_t)B*4, stream);
  hipMemsetAsync(gcnt,    0, (size_t)B*4, stream);

  int gE = (E+255)/256, gN = (N+255)/256;
  int nb1 = (N+1023)/1024;
  k_count<<<gE,256,0,stream>>>(src, dst, E, cnt_out, cnt_in);
  k_scan1<<<nb1,256,0,stream>>>(cnt_in, partial, N);
  k_scan2<<<1,256,0,stream>>>(partial, csr_off, nb1, N);
  k_scan3<<<nb1,256,0,stream>>>(cnt_in, partial, csr_off, N);
  k_prep<<<gN,256,0,stream>>>(cnt_out, cnt_in, csr_off, n_index, no, ni, csr_pos, gcnt, N);
  k_fill<<<gE,256,0,stream>>>(src, dst, E, csr_pos, csr_src, csr_eid);

  k_cond<<<B,256,0,stream>>>(t, t_w1, t_b1, t_w2, t_b2, cond);
  k_gemm_f32<256><<<dim3(B/64,12),256,0,stream>>>(cond, HDIM, film2_w, 512, film2_b,
                                                  gbX, HDIM, B, 1, nullptr);

  k_w2b<<<NLAYERS*HDIM*HDIM/256,256,0,stream>>>(conv2_w, Wthi, Wtlo);
  k_wcat<<<64,256,0,stream>>>(in_conv_w, edge_w, edge_b, wcat);
  k_init_agg<<<(N+3)/4,256,0,stream>>>(node_x, edge_e, csr_off, csr_src, csr_eid,
                                       no, ni, cnt_in, A48, N);
  k_gemm_f32<64><<<Npad/64,256,0,stream>>>(A48, 64, wcat, HDIM, in_conv_b,
                                           nullptr, HDIM, N, 0, hbf);

  for(int i=0;i<NLAYERS;i++){
    k_gather_bf<<<Npad/4,256,0,stream>>>(hbf, csr_off, csr_src, no, ni, agg_hi,
                                         N, Npad, fullTiles);
    if(i < NLAYERS-1)
      k_layer_mfma<false><<<Npad/64,256,0,stream>>>(agg_hi,
          Wthi + (size_t)i*HDIM*HDIM, Wtlo + (size_t)i*HDIM*HDIM,
          conv2_b + (size_t)i*HDIM,
          ln2_g + (size_t)i*HDIM, ln2_b + (size_t)i*HDIM,
          gbX + (size_t)(2*i)*B*HDIM, gbX + (size_t)(2*i+1)*B*HDIM,
          n_index, hbf, head_w, gsum, N);
    else
      k_layer_mfma<true><<<Npad/64,256,0,stream>>>(agg_hi,
          Wthi + (size_t)i*HDIM*HDIM, Wtlo + (size_t)i*HDIM*HDIM,
          conv2_b + (size_t)i*HDIM,
          ln2_g + (size_t)i*HDIM, ln2_b + (size_t)i*HDIM,
          gbX + (size_t)(2*i)*B*HDIM, gbX + (size_t)(2*i+1)*B*HDIM,
          n_index, hbf, head_w, gsum, N);
  }

  k_final<<<(B+255)/256,256,0,stream>>>(gsum, gcnt, head_b, (float*)d_out, B);
}